// Round 2
// baseline (6485.300 us; speedup 1.0000x reference)
//
#include <hip/hip_runtime.h>
#include <stdint.h>

// R5: R4 structure + low-traffic counter synchronization.
//  - Full barriers: monotone atomicAdd counter (1 add + 1 poller/WG on ONE LLC
//    line) replacing R4's all-poll (128x128 spin loads = fabric flood, the
//    measured FETCH_SIZE 115->467MB regression).
//  - Mini-barrier (Z3P ready): counter Z3C, target 8*tok.
//  - Barrier #4 removed: KB/VB WAR already protected by mini (attn WGs read
//    KB/VB before Z3C add). New-token embed (8 WGs, S1 of t+1) polls SC >=
//    128*n before reading SLOTS[n]; writer orders atomicMax -> SC add by
//    consuming the atomicMax return value (vmcnt drain) first.
//  Stage layout per iter: S1 -> B1 -> S2 -> B2 -> S3 -> B3 -> S4(attn 8WG,
//  mini, logits, argmax, SC add) -> S1(t+1)...

#define NWG 128
#define NT 256

__device__ __forceinline__ float ld_c(const float* p){
  return __hip_atomic_load(p, __ATOMIC_RELAXED, __HIP_MEMORY_SCOPE_AGENT);
}
__device__ __forceinline__ void st_c(float* p, float v){
  __hip_atomic_store(p, v, __ATOMIC_RELAXED, __HIP_MEMORY_SCOPE_AGENT);
}
__device__ __forceinline__ unsigned int ld_u(const unsigned int* p){
  return __hip_atomic_load(p, __ATOMIC_RELAXED, __HIP_MEMORY_SCOPE_AGENT);
}

__device__ __forceinline__ float wredsum(float v){
#pragma unroll
  for (int m=32;m;m>>=1) v += __shfl_xor(v,m,64);
  return v;
}
__device__ __forceinline__ float wredmax(float v){
#pragma unroll
  for (int m=32;m;m>>=1) v = fmaxf(v,__shfl_xor(v,m,64));
  return v;
}
__device__ __forceinline__ unsigned long long shflx64(unsigned long long v,int m){
  unsigned int lo=(unsigned int)(v&0xffffffffull), hi=(unsigned int)(v>>32);
  lo=__shfl_xor(lo,m,64); hi=__shfl_xor(hi,m,64);
  return (((unsigned long long)hi)<<32)|(unsigned long long)lo;
}

__device__ __forceinline__ float pe_val(int l, int e){
  int j = e >> 1;
  float dv = expf((float)(2*j) * (-0.035977892078031970f));
  float arg = (float)l * dv;
  return (e & 1) ? cosf(arg) : sinf(arg);
}

// fenced master barrier (prelude only): publishes normal cached stores;
// launch-idempotent (!= compare tolerates arbitrary leftover flag values).
__device__ __forceinline__ void gbar_f(int* arr, int* rel, int ep){
  __syncthreads();
  if (threadIdx.x==0){
    __builtin_amdgcn_fence(__ATOMIC_RELEASE, "agent");
    __hip_atomic_store(arr + blockIdx.x*16, ep, __ATOMIC_RELAXED, __HIP_MEMORY_SCOPE_AGENT);
  }
  if (blockIdx.x==0){
    if (threadIdx.x < NWG){
      while (__hip_atomic_load(arr + threadIdx.x*16, __ATOMIC_RELAXED, __HIP_MEMORY_SCOPE_AGENT) != ep)
        __builtin_amdgcn_s_sleep(1);
    }
    __syncthreads();
    if (threadIdx.x==0)
      __hip_atomic_store(rel, ep, __ATOMIC_RELAXED, __HIP_MEMORY_SCOPE_AGENT);
  }
  if (threadIdx.x==0){
    while (__hip_atomic_load(rel, __ATOMIC_RELAXED, __HIP_MEMORY_SCOPE_AGENT) != ep)
      __builtin_amdgcn_s_sleep(1);
    __builtin_amdgcn_fence(__ATOMIC_ACQUIRE, "agent");
  }
  __syncthreads();
}

// loop barrier: monotone counter. __syncthreads drains vmcnt (sc1 stores are
// LLC-visible once retired), then one arrive-add + one poller per WG on a
// single LLC line. target = epoch*NWG; counter never reset during the launch.
__device__ __forceinline__ void gbar3(unsigned int* cnt, unsigned int target){
  __syncthreads();
  if (threadIdx.x==0){
    __hip_atomic_fetch_add(cnt, 1u, __ATOMIC_RELAXED, __HIP_MEMORY_SCOPE_AGENT);
    while (ld_u(cnt) < target) __builtin_amdgcn_s_sleep(1);
  }
  __syncthreads();
}

extern "C" __global__ __launch_bounds__(256, 2)
void gen18124_kernel(const float* __restrict__ noise,
                     const float* __restrict__ iw, const float* __restrict__ ib,
                     const float* __restrict__ Wq, const float* __restrict__ bq,
                     const float* __restrict__ Wk, const float* __restrict__ bk,
                     const float* __restrict__ Wv, const float* __restrict__ bv,
                     const float* __restrict__ Wo, const float* __restrict__ bo,
                     const float* __restrict__ lng, const float* __restrict__ lnb,
                     const float* __restrict__ emb, const float* __restrict__ sw,
                     const float* __restrict__ sb,
                     int* __restrict__ out, float* __restrict__ ws)
{
  const float ISQ = 0.17677669529663687f; // 1/sqrt(32)
  __shared__ float xs[1024];     // R1 rows (4x256), persistent S1 -> S3
  __shared__ float qs[128];      // Q0 rows (4x32),  persistent S1 -> S2
  __shared__ float qn1[32];      // Q1 row n,        persistent S3 -> S4
  __shared__ float m8s[32];      // S1 per-row per-head softmax moments
  __shared__ float wvl[64];      // WVEC copy
  __shared__ float sm[4800];     // per-stage scratch
  __shared__ unsigned long long redU[4];
  extern __shared__ float swl[]; // [256][128] soft_W slice, 128KB

  // ---- workspace layout (floats) ----
  float* WVEC = ws;              // 64
  float* SKC  = ws+64;           // [2][256]
  float* SVC  = ws+576;          // [2][256]
  float* KAP  = ws+1088;         // [2][8][256]
  float* UT   = ws+5184;         // [2][8][256]
  float* CC   = ws+9280;         // [2][256]
  float* BETA = ws+9792;         // [2][8]
  unsigned long long* SLOTS = (unsigned long long*)(ws+9824); // [64]
  unsigned int* Z3C = (unsigned int*)(ws+9952);   // own 64B line
  unsigned int* CNT = (unsigned int*)(ws+9968);   // own 64B line
  unsigned int* SC  = (unsigned int*)(ws+9984);   // own 64B line
  int* ARR  = (int*)(ws+10080);  // 128 * stride16 (prelude master barrier)
  int* REL  = (int*)(ws+12128);
  float* Yg  = ws+14208;         // [64][256]
  float* R2  = ws+30592;         // [64][256] (only row n used per iter)
  float* KB  = ws+46976;         // [64][256] (self0 then self1)
  float* VB  = ws+63360;         // [64][256]
  float* Z2P = ws+79744;         // [8][64][256]
  float* Z3P = ws+210816;        // [8][256]

  const int g = blockIdx.x, t = threadIdx.x;
  int ep = 0;
  unsigned int bep = 0;

  // ---- soft_W slice -> LDS (WG-private) ----
  {
    const int base = g*125;
#pragma unroll 8
    for (int i=t; i<256*128; i+=NT){
      int e=i>>7, c=i&127;
      float val = 0.f;
      if (c<125) val = sw[e*16000 + base + c];
      swl[i]=val;
    }
  }

  // ================= Prelude A: colsums, wvec, Y0, flag init =================
  {
    int c0 = 2*g;
    float a0=Wk[t*256+c0],       a1=Wk[t*256+c0+1];
    float a2=Wk[65536+t*256+c0], a3=Wk[65536+t*256+c0+1];
    float a4=Wv[t*256+c0],       a5=Wv[t*256+c0+1];
    float a6=Wv[65536+t*256+c0], a7=Wv[65536+t*256+c0+1];
    a0=wredsum(a0); a1=wredsum(a1); a2=wredsum(a2); a3=wredsum(a3);
    a4=wredsum(a4); a5=wredsum(a5); a6=wredsum(a6); a7=wredsum(a7);
    int lane=t&63, wid=t>>6;
    if (lane==0){
      sm[wid*8+0]=a0; sm[wid*8+1]=a1; sm[wid*8+2]=a2; sm[wid*8+3]=a3;
      sm[wid*8+4]=a4; sm[wid*8+5]=a5; sm[wid*8+6]=a6; sm[wid*8+7]=a7;
    }
    __syncthreads();
    if (t<8){
      float s=sm[t]+sm[8+t]+sm[16+t]+sm[24+t];
      if (t<4) SKC[(t>>1)*256 + c0 + (t&1)] = s;
      else     SVC[((t-4)>>1)*256 + c0 + ((t-4)&1)] = s;
    }
    __syncthreads();
    if (g==0){
      // zero per-launch sync state (published by gbar_f below)
      if (t<64) SLOTS[t]=0ull;
      if (t==0){ *Z3C=0u; *CNT=0u; *SC=0u; }
      float* wl = sm+64;
      if (t<64) wl[t] = noise[t];
      __syncthreads();
      for (int i=0;i<4;i++){
        float acc=0.f;
        if (t<64){
          for (int in_=0;in_<64;in_++) acc += wl[in_]*iw[(i*64+in_)*64+t];
          acc += ib[i*64+t];
        }
        __syncthreads();
        if (t<64) wl[t]=acc;
        __syncthreads();
      }
      if (t<64) WVEC[t]=wl[t];
    }
    if (g==1){
      Yg[t] = emb[t] + pe_val(0,t);
      if (t==0) out[0]=0;
    }
  }
  gbar_f(ARR,REL,++ep);

  // ================= Prelude B: KAP / UT / CC / BETA tables =================
  {
    int c0 = 2*g;
    float p00 = bv[t]    *Wo[t*256+c0],        p01 = bv[t]    *Wo[t*256+c0+1];
    float p10 = bv[256+t]*Wo[65536+t*256+c0],  p11 = bv[256+t]*Wo[65536+t*256+c0+1];
    p00=wredsum(p00); p01=wredsum(p01); p10=wredsum(p10); p11=wredsum(p11);
    int lane=t&63, wid=t>>6;
    if (lane==0){ sm[wid*4+0]=p00; sm[wid*4+1]=p01; sm[wid*4+2]=p10; sm[wid*4+3]=p11; }
    __syncthreads();
    if (t<4){
      float s=sm[t]+sm[4+t]+sm[8+t]+sm[12+t];
      int i=t>>1, cl=t&1;
      CC[i*256+c0+cl] = s + bo[i*256+c0+cl];
    }
    if (t<32){
      int i=t>>4, h=(t>>1)&7, c=c0+(t&1);
      float s=0.f;
      for (int e2=0;e2<32;e2++) s += SVC[i*256+h*32+e2]*Wo[i*65536+(h*32+e2)*256+c];
      UT[(i*8+h)*256+c]=s;
    }
    if (t>=32 && t<64){
      int u=t-32, i=u>>4, h=(u>>1)&7, e=c0+(u&1);
      float s=0.f;
      for (int c2=0;c2<32;c2++) s += Wq[i*65536+e*256+h*32+c2]*SKC[i*256+h*32+c2];
      KAP[(i*8+h)*256+e]=s;
    }
    if (g==0 && t>=64 && t<80){
      int u=t-64, i=u>>3, h=u&7;
      float s=0.f;
      for (int c2=0;c2<32;c2++) s += bq[i*256+h*32+c2]*SKC[i*256+h*32+c2];
      BETA[i*8+h]=s;
    }
  }
  gbar_f(ARR,REL,++ep);

  if (t<64) wvl[t]=WVEC[t];
  __syncthreads();

  const int h  = g&7;
  const int rg = g>>3;

  // ================= decode loop: 3 counter barriers + mini + SC =================
  for (int tok=1; tok<64; tok++){
    const int n = tok-1;

    // ---- S1: R1 for own 4 rows (wave-per-row) + self0 Q/K/V proj ----
    {
      const int j=t>>6, l=t&63, l8=l&7, h2=l>>3;
      const int q=rg+16*j;
      if (q<tok){
        float* x = xs + j*256;
        if (q==n && tok>1){
          // wait for all 128 argmax contributions of iteration n
          while (ld_u(SC) < (unsigned)(128*n)) __builtin_amdgcn_s_sleep(1);
          unsigned long long s = __hip_atomic_load(&SLOTS[n], __ATOMIC_RELAXED, __HIP_MEMORY_SCOPE_AGENT);
          int v = (int)(~(unsigned int)(s & 0xffffffffull));
          if (h==0 && l==0) out[q]=v;
#pragma unroll
          for (int ii=0;ii<4;ii++){
            int e=l+64*ii;
            float yv = emb[v*256+e] + pe_val(q,e);
            x[e]=yv;
            if (h==0) st_c(&Yg[q*256+e], yv);
          }
        } else {
#pragma unroll
          for (int ii=0;ii<4;ii++){ int e=l+64*ii; x[e]=ld_c(&Yg[q*256+e]); }
        }
        float wreg[8];
#pragma unroll
        for (int m=0;m<8;m++) wreg[m]=wvl[l8+8*m];
#pragma unroll
        for (int b=0;b<2;b++){
          float part=0.f;
#pragma unroll 8
          for (int jj=l8; jj<256; jj+=8) part += x[jj]*KAP[(b*8+h2)*256+jj];
          part += __shfl_xor(part,1,64);
          part += __shfl_xor(part,2,64);
          part += __shfl_xor(part,4,64);
          float alpha=(part+BETA[b*8+h2])*ISQ;
          float mx=-3.4e38f;
#pragma unroll
          for (int m=0;m<8;m++){ int k=l8+8*m; if (k<tok) mx=fmaxf(mx, alpha*wreg[m]); }
          mx=fmaxf(mx,__shfl_xor(mx,1,64));
          mx=fmaxf(mx,__shfl_xor(mx,2,64));
          mx=fmaxf(mx,__shfl_xor(mx,4,64));
          float num=0.f, den=0.f;
#pragma unroll
          for (int m=0;m<8;m++){
            int k=l8+8*m;
            if (k<tok){ float e_=expf(alpha*wreg[m]-mx); num+=e_*wreg[m]; den+=e_; }
          }
          num+=__shfl_xor(num,1,64); num+=__shfl_xor(num,2,64); num+=__shfl_xor(num,4,64);
          den+=__shfl_xor(den,1,64); den+=__shfl_xor(den,2,64); den+=__shfl_xor(den,4,64);
          if (l8==0) m8s[j*8+h2]=num/den;
          float zvv[4], s_=0.f, sq_=0.f;
#pragma unroll
          for (int ii=0;ii<4;ii++){
            int e=l+64*ii;
            float z=CC[b*256+e]+x[e];
#pragma unroll
            for (int hh=0;hh<8;hh++) z += m8s[j*8+hh]*UT[(b*8+hh)*256+e];
            zvv[ii]=z; s_+=z; sq_+=z*z;
          }
          s_=wredsum(s_); sq_=wredsum(sq_);
          float mu=s_*(1.f/256.f), var=sq_*(1.f/256.f)-mu*mu, rstd=1.f/sqrtf(var+1e-5f);
#pragma unroll
          for (int ii=0;ii<4;ii++){
            int e=l+64*ii;
            x[e]=(zvv[ii]-mu)*rstd*lng[b*256+e]+lnb[b*256+e];
          }
        }
      }
      __syncthreads();   // xs (R1 rows) ready for all 4 waves
      // self0 Q/K/V projection, head h, 4 rows (Q -> LDS only)
      int c=t&31, epp=t>>5;
      const int col=h*32+c;
      float aq[4]={0,0,0,0}, ak[4]={0,0,0,0}, av[4]={0,0,0,0};
#pragma unroll 8
      for (int e=epp*32; e<epp*32+32; e++){
        float wq_=Wq[e*256+col], wk_=Wk[e*256+col], wv_=Wv[e*256+col];
#pragma unroll
        for (int jj=0;jj<4;jj++){ float r=xs[jj*256+e]; aq[jj]+=r*wq_; ak[jj]+=r*wk_; av[jj]+=r*wv_; }
      }
#pragma unroll
      for (int jj=0;jj<4;jj++){
        aq[jj]+=__shfl_xor(aq[jj],32,64);
        ak[jj]+=__shfl_xor(ak[jj],32,64);
        av[jj]+=__shfl_xor(av[jj],32,64);
      }
      float4* redq=(float4*)(sm+1056); float4* redk=(float4*)(sm+1568); float4* redv4=(float4*)(sm+2080);
      int lane=t&63, wid=t>>6;
      if (lane<32){
        redq[wid*32+lane]=make_float4(aq[0],aq[1],aq[2],aq[3]);
        redk[wid*32+lane]=make_float4(ak[0],ak[1],ak[2],ak[3]);
        redv4[wid*32+lane]=make_float4(av[0],av[1],av[2],av[3]);
      }
      __syncthreads();
      if (t<32){
        float4 A=redq[t],B4=redq[32+t],C4=redq[64+t],D4=redq[96+t];
        float sq[4]={A.x+B4.x+C4.x+D4.x, A.y+B4.y+C4.y+D4.y, A.z+B4.z+C4.z+D4.z, A.w+B4.w+C4.w+D4.w};
        A=redk[t];B4=redk[32+t];C4=redk[64+t];D4=redk[96+t];
        float sk[4]={A.x+B4.x+C4.x+D4.x, A.y+B4.y+C4.y+D4.y, A.z+B4.z+C4.z+D4.z, A.w+B4.w+C4.w+D4.w};
        A=redv4[t];B4=redv4[32+t];C4=redv4[64+t];D4=redv4[96+t];
        float sv[4]={A.x+B4.x+C4.x+D4.x, A.y+B4.y+C4.y+D4.y, A.z+B4.z+C4.z+D4.z, A.w+B4.w+C4.w+D4.w};
        int cc=h*32+t;
        float bq_=bq[cc], bk_=bk[cc], bv_=bv[cc];
#pragma unroll
        for (int jj=0;jj<4;jj++){
          qs[jj*32+t]=sq[jj]+bq_;
          int q_=rg+16*jj;
          if (q_<tok){
            st_c(&KB[q_*256+cc], sk[jj]+bk_);
            st_c(&VB[q_*256+cc], sv[jj]+bv_);
          }
        }
      }
    }
    gbar3(CNT,(++bep)*NWG);

    // ---- S2: self0 attention + per-head partial O-proj -> Z2P ----
    {
      float* Ks=sm; float* Vs=sm+2112; float* arow=sm+4352; float* o2s=sm+4608;
      int k=t>>2, f0=(t&3)*8;
      if (k<tok){
#pragma unroll
        for (int i2=0;i2<8;i2++){
          Ks[k*33+f0+i2]=ld_c(&KB[k*256+h*32+f0+i2]);
          Vs[k*33+f0+i2]=ld_c(&VB[k*256+h*32+f0+i2]);
        }
      }
      __syncthreads();
      int w=t>>6, lane=t&63; int q_=rg+16*w; bool ok=q_<tok;
      float sc=-3.4e38f;
      if (ok && lane<tok){
        sc=0.f;
#pragma unroll
        for (int c2=0;c2<32;c2++) sc+=qs[w*32+c2]*Ks[lane*33+c2];
        sc*=ISQ;
      }
      float mx=wredmax(sc);
      float ex=(ok&&lane<tok)? expf(sc-mx):0.f;
      float sd=wredsum(ex);
      arow[w*64+lane]= ok ? ex/sd : 0.f;
      __syncthreads();
      int jl=lane&31, half=lane>>5;
      float oa=0.f;
      if (ok){ for (int k2=half;k2<tok;k2+=2) oa+=arow[w*64+k2]*Vs[k2*33+jl]; }
      oa += __shfl_xor(oa,32,64);
      if (lane<32) o2s[w*32+jl]=oa;
      __syncthreads();
      float acc[4]={0,0,0,0};
#pragma unroll 8
      for (int j2=0;j2<32;j2++){
        float wv_=Wo[(h*32+j2)*256+t];
#pragma unroll
        for (int jj=0;jj<4;jj++) acc[jj]+=o2s[jj*32+j2]*wv_;
      }
#pragma unroll
      for (int jj=0;jj<4;jj++){ int q2=rg+16*jj; if (q2<tok) st_c(&Z2P[(h*64+q2)*256+t], acc[jj]); }
    }
    gbar3(CNT,(++bep)*NWG);

    // ---- S3: z2 assemble + LN -> R2[n] ; self1 K/V proj (+Q1 row n -> LDS) ----
    {
      float* rows4=sm; float* mus=sm+1024;
#pragma unroll
      for (int jj=0;jj<4;jj++){
        int q_=rg+16*jj;
        float z = bo[t] + xs[jj*256+t];
#pragma unroll
        for (int h2=0;h2<8;h2++) z += ld_c(&Z2P[(h2*64+q_)*256+t]);
        rows4[jj*256+t]=z;
      }
      __syncthreads();
      {
        int w=t>>6, lane=t&63;
        float v0=rows4[w*256+lane], v1=rows4[w*256+64+lane], v2=rows4[w*256+128+lane], v3=rows4[w*256+192+lane];
        float s=v0+v1+v2+v3, sq2=v0*v0+v1*v1+v2*v2+v3*v3;
        s=wredsum(s); sq2=wredsum(sq2);
        if (lane==0){
          float mu=s*(1.f/256.f);
          float var=sq2*(1.f/256.f)-mu*mu;
          mus[w*2]=mu; mus[w*2+1]=1.f/sqrtf(var+1e-5f);
        }
      }
      __syncthreads();
#pragma unroll
      for (int jj=0;jj<4;jj++){
        float mu=mus[jj*2], rstd=mus[jj*2+1];
        float val=(rows4[jj*256+t]-mu)*rstd*lng[t]+lnb[t];
        rows4[jj*256+t]=val;
        int q_=rg+16*jj;
        if (h==0 && q_==n) st_c(&R2[q_*256+t], val);
      }
      __syncthreads();
      int c=t&31, epp=t>>5;
      const int col=h*32+c;
      float aq[4]={0,0,0,0}, ak[4]={0,0,0,0}, av[4]={0,0,0,0};
#pragma unroll 8
      for (int e=epp*32; e<epp*32+32; e++){
        float wq_=Wq[65536+e*256+col], wk_=Wk[65536+e*256+col], wv_=Wv[65536+e*256+col];
#pragma unroll
        for (int jj=0;jj<4;jj++){ float r=rows4[jj*256+e]; aq[jj]+=r*wq_; ak[jj]+=r*wk_; av[jj]+=r*wv_; }
      }
#pragma unroll
      for (int jj=0;jj<4;jj++){
        aq[jj]+=__shfl_xor(aq[jj],32,64);
        ak[jj]+=__shfl_xor(ak[jj],32,64);
        av[jj]+=__shfl_xor(av[jj],32,64);
      }
      float4* redq=(float4*)(sm+1056); float4* redk=(float4*)(sm+1568); float4* redv4=(float4*)(sm+2080);
      int lane=t&63, wid=t>>6;
      if (lane<32){
        redq[wid*32+lane]=make_float4(aq[0],aq[1],aq[2],aq[3]);
        redk[wid*32+lane]=make_float4(ak[0],ak[1],ak[2],ak[3]);
        redv4[wid*32+lane]=make_float4(av[0],av[1],av[2],av[3]);
      }
      __syncthreads();
      if (t<32){
        float4 A=redq[t],B4=redq[32+t],C4=redq[64+t],D4=redq[96+t];
        float sq[4]={A.x+B4.x+C4.x+D4.x, A.y+B4.y+C4.y+D4.y, A.z+B4.z+C4.z+D4.z, A.w+B4.w+C4.w+D4.w};
        A=redk[t];B4=redk[32+t];C4=redk[64+t];D4=redk[96+t];
        float sk[4]={A.x+B4.x+C4.x+D4.x, A.y+B4.y+C4.y+D4.y, A.z+B4.z+C4.z+D4.z, A.w+B4.w+C4.w+D4.w};
        A=redv4[t];B4=redv4[32+t];C4=redv4[64+t];D4=redv4[96+t];
        float sv[4]={A.x+B4.x+C4.x+D4.x, A.y+B4.y+C4.y+D4.y, A.z+B4.z+C4.z+D4.z, A.w+B4.w+C4.w+D4.w};
        int cc=h*32+t;
#pragma unroll
        for (int jj=0;jj<4;jj++){
          int q_=rg+16*jj;
          if (q_<tok){
            st_c(&KB[q_*256+cc], sk[jj]+bk[256+cc]);
            st_c(&VB[q_*256+cc], sv[jj]+bv[256+cc]);
          }
          if (q_==n) qn1[t]=sq[jj]+bq[256+cc];
        }
      }
    }
    gbar3(CNT,(++bep)*NWG);

    // ---- S4: self1 attn row n (8 WGs -> Z3P + Z3C) ; all: z3 LN + logits + argmax ----
    {
      float resid = ld_c(&R2[n*256+t]);   // early issue; valid after B3
      if (rg == (n&15)){
        float* Ks=sm; float* Vs=sm+2112; float* arow=sm+4352; float* o3s=sm+4608;
        int k=t>>2, f0=(t&3)*8;
        if (k<tok){
#pragma unroll
          for (int i2=0;i2<8;i2++){
            Ks[k*33+f0+i2]=ld_c(&KB[k*256+h*32+f0+i2]);
            Vs[k*33+f0+i2]=ld_c(&VB[k*256+h*32+f0+i2]);
          }
        }
        __syncthreads();
        int lane=t&63, w=t>>6;
        if (w==0){
          float sc=-3.4e38f;
          if (lane<tok){
            sc=0.f;
#pragma unroll
            for (int c2=0;c2<32;c2++) sc+=qn1[c2]*Ks[lane*33+c2];
            sc*=ISQ;
          }
          float mx=wredmax(sc);
          float ex=(lane<tok)? expf(sc-mx):0.f;
          float sd=wredsum(ex);
          arow[lane]=ex/sd;
        }
        __syncthreads();
        if (w==0){
          int jl=lane&31, half=lane>>5;
          float oa=0.f;
          for (int k2=half;k2<tok;k2+=2) oa+=arow[k2]*Vs[k2*33+jl];
          oa+=__shfl_xor(oa,32,64);
          if (lane<32) o3s[jl]=oa;
        }
        __syncthreads();
        float acc=0.f;
#pragma unroll 8
        for (int j2=0;j2<32;j2++) acc+=o3s[j2]*Wo[65536+(h*32+j2)*256+t];
        st_c(&Z3P[h*256+t], acc);
        __syncthreads();            // drain Z3P stores to LLC
        if (t==0)
          __hip_atomic_fetch_add(Z3C, 1u, __ATOMIC_RELAXED, __HIP_MEMORY_SCOPE_AGENT);
      }
      // mini-barrier: wait for the 8 head partials (counter monotone, 8/iter)
      if (t==0){ while (ld_u(Z3C) < (unsigned)(8*tok)) __builtin_amdgcn_s_sleep(1); }
      __syncthreads();
      float* outn=sm; float* redv=sm+256; float* pp=sm+512;
      float z = bo[256+t] + resid;
#pragma unroll
      for (int h2=0;h2<8;h2++) z += ld_c(&Z3P[h2*256+t]);
      float s=wredsum(z), sq2=wredsum(z*z);
      int lane=t&63, wid=t>>6;
      if (lane==0){ redv[wid]=s; redv[4+wid]=sq2; }
      __syncthreads();
      float ts=redv[0]+redv[1]+redv[2]+redv[3];
      float tq=redv[4]+redv[5]+redv[6]+redv[7];
      float mu=ts*(1.f/256.f);
      float var=tq*(1.f/256.f)-mu*mu;
      float rstd=1.f/sqrtf(var+1e-5f);
      outn[t]=(z-mu)*rstd*lng[256+t]+lnb[256+t];
      __syncthreads();
      const int c = t & 127, half = t >> 7;
      float acc = 0.f;
      if (c < 125){
        const int e0 = half*128;
#pragma unroll 8
        for (int e=e0; e<e0+128; e++) acc += outn[e]*swl[e*128+c];
      }
      if (half==1 && c<125) pp[c]=acc;
      __syncthreads();
      unsigned long long key=0ull;
      if (half==0 && c<125){
        int v=g*125+c;
        float a2 = acc + pp[c] + sb[v];
        unsigned int fb=__float_as_uint(a2);
        fb = (fb&0x80000000u)? ~fb : (fb|0x80000000u);
        key=(((unsigned long long)fb)<<32) | (unsigned long long)(~(unsigned int)v);
      }
#pragma unroll
      for (int m=32;m;m>>=1){
        unsigned long long o=shflx64(key,m);
        key = (o>key)? o : key;
      }
      if (lane==0) redU[wid]=key;
      __syncthreads();
      if (t==0){
        unsigned long long kk=redU[0];
        if (redU[1]>kk) kk=redU[1];
        if (redU[2]>kk) kk=redU[2];
        if (redU[3]>kk) kk=redU[3];
        // returning atomicMax: consuming the result forces vmcnt drain, so the
        // max is applied at LLC before the SC increment below is issued.
        unsigned long long old_ = atomicMax(&SLOTS[tok], kk);
        asm volatile("" :: "v"((unsigned int)old_), "v"((unsigned int)(old_>>32)));
        __hip_atomic_fetch_add(SC, 1u, __ATOMIC_RELAXED, __HIP_MEMORY_SCOPE_AGENT);
      }
    }
    // no full barrier here: KB/VB WAR covered by the mini-barrier (attn reads
    // precede Z3C add); SLOTS readers gate on SC in S1 of the next iteration.
  }

  // epilogue: final winner (wait for all 128 contributions of iter 63)
  if (g==0 && t==0){
    while (ld_u(SC) < (unsigned)(128*63)) __builtin_amdgcn_s_sleep(1);
    unsigned long long s=__hip_atomic_load(&SLOTS[63],__ATOMIC_RELAXED,__HIP_MEMORY_SCOPE_AGENT);
    out[63]=(int)(~(unsigned int)(s&0xffffffffull));
  }
}

extern "C" void kernel_launch(void* const* d_in, const int* in_sizes, int n_in,
                              void* d_out, int out_size, void* d_ws, size_t ws_size,
                              hipStream_t stream)
{
  (void)in_sizes; (void)n_in; (void)out_size; (void)ws_size;
  hipLaunchKernelGGL(gen18124_kernel, dim3(NWG), dim3(NT), 131072, stream,
    (const float*)d_in[0],  (const float*)d_in[1],  (const float*)d_in[2],
    (const float*)d_in[3],  (const float*)d_in[4],  (const float*)d_in[5],
    (const float*)d_in[6],  (const float*)d_in[7],  (const float*)d_in[8],
    (const float*)d_in[9],  (const float*)d_in[10], (const float*)d_in[11],
    (const float*)d_in[12], (const float*)d_in[13], (const float*)d_in[14],
    (const float*)d_in[15], (int*)d_out, (float*)d_ws);
}

// Round 3
// 6239.568 us; speedup vs baseline: 1.0394x; 1.0394x over previous
//
#include <hip/hip_runtime.h>
#include <stdint.h>

// R6: 4-stage structure (R4) + R3's proven master/release fence-free barrier.
//  Post-mortem R4/R5: both all-poll (R4) and single-counter (R5) barriers
//  congest one LLC line (N^2 poll re-fetches / 128 serialized RMWs) -> 6+ ms,
//  FETCH ~450MB. R3's master/release uses distinct arrive lines (parallel
//  stores), parallel master scan, one broadcast release line -> keep that.
//  - 4 loop barriers: after S1, S2, S3, S4 (S4 barrier replaces R5's SC
//    counter; it also orders SLOTS[n] atomicMax before S1(t+1) reads).
//  - Z3F 8-flag mini-barrier inside S4 (distinct lines, monotone value=tok,
//    zeroed each launch).
//  Stage layout per iter: S1(R1 in-LDS + QKV0) -> B -> S2(attn0->Z2P) -> B ->
//  S3(z2+LN->R2[n], KV1 proj, Q1->LDS) -> B -> S4(attn1 8WG, mini, logits,
//  argmax) -> B.

#define NWG 128
#define NT 256

__device__ __forceinline__ float ld_c(const float* p){
  return __hip_atomic_load(p, __ATOMIC_RELAXED, __HIP_MEMORY_SCOPE_AGENT);
}
__device__ __forceinline__ void st_c(float* p, float v){
  __hip_atomic_store(p, v, __ATOMIC_RELAXED, __HIP_MEMORY_SCOPE_AGENT);
}
__device__ __forceinline__ int ld_fi(const int* p){
  return __hip_atomic_load(p, __ATOMIC_RELAXED, __HIP_MEMORY_SCOPE_AGENT);
}
__device__ __forceinline__ void st_fi(int* p, int v){
  __hip_atomic_store(p, v, __ATOMIC_RELAXED, __HIP_MEMORY_SCOPE_AGENT);
}

__device__ __forceinline__ float wredsum(float v){
#pragma unroll
  for (int m=32;m;m>>=1) v += __shfl_xor(v,m,64);
  return v;
}
__device__ __forceinline__ float wredmax(float v){
#pragma unroll
  for (int m=32;m;m>>=1) v = fmaxf(v,__shfl_xor(v,m,64));
  return v;
}
__device__ __forceinline__ unsigned long long shflx64(unsigned long long v,int m){
  unsigned int lo=(unsigned int)(v&0xffffffffull), hi=(unsigned int)(v>>32);
  lo=__shfl_xor(lo,m,64); hi=__shfl_xor(hi,m,64);
  return (((unsigned long long)hi)<<32)|(unsigned long long)lo;
}

__device__ __forceinline__ float pe_val(int l, int e){
  int j = e >> 1;
  float dv = expf((float)(2*j) * (-0.035977892078031970f));
  float arg = (float)l * dv;
  return (e & 1) ? cosf(arg) : sinf(arg);
}

// fenced master barrier (prelude only): publishes normal cached stores;
// launch-idempotent (!= compare tolerates arbitrary leftover flag values).
__device__ __forceinline__ void gbar_f(int* arr, int* rel, int ep){
  __syncthreads();
  if (threadIdx.x==0){
    __builtin_amdgcn_fence(__ATOMIC_RELEASE, "agent");
    __hip_atomic_store(arr + blockIdx.x*16, ep, __ATOMIC_RELAXED, __HIP_MEMORY_SCOPE_AGENT);
  }
  if (blockIdx.x==0){
    if (threadIdx.x < NWG){
      while (__hip_atomic_load(arr + threadIdx.x*16, __ATOMIC_RELAXED, __HIP_MEMORY_SCOPE_AGENT) != ep)
        __builtin_amdgcn_s_sleep(1);
    }
    __syncthreads();
    if (threadIdx.x==0)
      __hip_atomic_store(rel, ep, __ATOMIC_RELAXED, __HIP_MEMORY_SCOPE_AGENT);
  }
  if (threadIdx.x==0){
    while (__hip_atomic_load(rel, __ATOMIC_RELAXED, __HIP_MEMORY_SCOPE_AGENT) != ep)
      __builtin_amdgcn_s_sleep(1);
    __builtin_amdgcn_fence(__ATOMIC_ACQUIRE, "agent");
  }
  __syncthreads();
}

// fence-free master/release barrier (decode loop): all cross-WG data moves via
// sc1 atomics; __syncthreads drains vmcnt so those stores are LLC-visible
// before the arrive flag. Distinct arrive lines -> parallel, uncontended.
__device__ __forceinline__ void gbar_nf(int* arr, int* rel, int ep){
  __syncthreads();
  if (threadIdx.x==0)
    __hip_atomic_store(arr + blockIdx.x*16, ep, __ATOMIC_RELAXED, __HIP_MEMORY_SCOPE_AGENT);
  if (blockIdx.x==0){
    if (threadIdx.x < NWG){
      while (__hip_atomic_load(arr + threadIdx.x*16, __ATOMIC_RELAXED, __HIP_MEMORY_SCOPE_AGENT) != ep)
        __builtin_amdgcn_s_sleep(1);
    }
    __syncthreads();
    if (threadIdx.x==0)
      __hip_atomic_store(rel, ep, __ATOMIC_RELAXED, __HIP_MEMORY_SCOPE_AGENT);
  }
  if (threadIdx.x==0){
    while (__hip_atomic_load(rel, __ATOMIC_RELAXED, __HIP_MEMORY_SCOPE_AGENT) != ep)
      __builtin_amdgcn_s_sleep(1);
  }
  __syncthreads();
}

extern "C" __global__ __launch_bounds__(256, 2)
void gen18124_kernel(const float* __restrict__ noise,
                     const float* __restrict__ iw, const float* __restrict__ ib,
                     const float* __restrict__ Wq, const float* __restrict__ bq,
                     const float* __restrict__ Wk, const float* __restrict__ bk,
                     const float* __restrict__ Wv, const float* __restrict__ bv,
                     const float* __restrict__ Wo, const float* __restrict__ bo,
                     const float* __restrict__ lng, const float* __restrict__ lnb,
                     const float* __restrict__ emb, const float* __restrict__ sw,
                     const float* __restrict__ sb,
                     int* __restrict__ out, float* __restrict__ ws)
{
  const float ISQ = 0.17677669529663687f; // 1/sqrt(32)
  __shared__ float xs[1024];     // R1 rows (4x256), persistent S1 -> S3
  __shared__ float qs[128];      // Q0 rows (4x32),  persistent S1 -> S2
  __shared__ float qn1[32];      // Q1 row n,        persistent S3 -> S4
  __shared__ float m8s[32];      // S1 per-row per-head softmax moments
  __shared__ float wvl[64];      // WVEC copy
  __shared__ float sm[4800];     // per-stage scratch
  __shared__ unsigned long long redU[4];
  extern __shared__ float swl[]; // [256][128] soft_W slice, 128KB

  // ---- workspace layout (floats) ----
  float* WVEC = ws;              // 64
  float* SKC  = ws+64;           // [2][256]
  float* SVC  = ws+576;          // [2][256]
  float* KAP  = ws+1088;         // [2][8][256]
  float* UT   = ws+5184;         // [2][8][256]
  float* CC   = ws+9280;         // [2][256]
  float* BETA = ws+9792;         // [2][8]
  unsigned long long* SLOTS = (unsigned long long*)(ws+9824); // [64]
  int* Z3F  = (int*)(ws+9952);   // 8 * stride16 (mini-barrier flags)
  int* ARR  = (int*)(ws+10080);  // 128 * stride16 (master barrier arrive)
  int* REL  = (int*)(ws+12128);
  float* Yg  = ws+14208;         // [64][256]
  float* R2  = ws+30592;         // [64][256] (only row n used per iter)
  float* KB  = ws+46976;         // [64][256] (self0 then self1)
  float* VB  = ws+63360;         // [64][256]
  float* Z2P = ws+79744;         // [8][64][256]
  float* Z3P = ws+210816;        // [8][256]

  const int g = blockIdx.x, t = threadIdx.x;
  int ep = 0;

  // ---- soft_W slice -> LDS (WG-private) ----
  {
    const int base = g*125;
#pragma unroll 8
    for (int i=t; i<256*128; i+=NT){
      int e=i>>7, c=i&127;
      float val = 0.f;
      if (c<125) val = sw[e*16000 + base + c];
      swl[i]=val;
    }
  }

  // ================= Prelude A: colsums, wvec, Y0, flag init =================
  {
    int c0 = 2*g;
    float a0=Wk[t*256+c0],       a1=Wk[t*256+c0+1];
    float a2=Wk[65536+t*256+c0], a3=Wk[65536+t*256+c0+1];
    float a4=Wv[t*256+c0],       a5=Wv[t*256+c0+1];
    float a6=Wv[65536+t*256+c0], a7=Wv[65536+t*256+c0+1];
    a0=wredsum(a0); a1=wredsum(a1); a2=wredsum(a2); a3=wredsum(a3);
    a4=wredsum(a4); a5=wredsum(a5); a6=wredsum(a6); a7=wredsum(a7);
    int lane=t&63, wid=t>>6;
    if (lane==0){
      sm[wid*8+0]=a0; sm[wid*8+1]=a1; sm[wid*8+2]=a2; sm[wid*8+3]=a3;
      sm[wid*8+4]=a4; sm[wid*8+5]=a5; sm[wid*8+6]=a6; sm[wid*8+7]=a7;
    }
    __syncthreads();
    if (t<8){
      float s=sm[t]+sm[8+t]+sm[16+t]+sm[24+t];
      if (t<4) SKC[(t>>1)*256 + c0 + (t&1)] = s;
      else     SVC[((t-4)>>1)*256 + c0 + ((t-4)&1)] = s;
    }
    __syncthreads();
    if (g==0){
      // zero per-launch sync state (published by gbar_f below)
      if (t<64) SLOTS[t]=0ull;
      if (t<8)  Z3F[t*16]=0;
      float* wl = sm+64;
      if (t<64) wl[t] = noise[t];
      __syncthreads();
      for (int i=0;i<4;i++){
        float acc=0.f;
        if (t<64){
          for (int in_=0;in_<64;in_++) acc += wl[in_]*iw[(i*64+in_)*64+t];
          acc += ib[i*64+t];
        }
        __syncthreads();
        if (t<64) wl[t]=acc;
        __syncthreads();
      }
      if (t<64) WVEC[t]=wl[t];
    }
    if (g==1){
      Yg[t] = emb[t] + pe_val(0,t);
      if (t==0) out[0]=0;
    }
  }
  gbar_f(ARR,REL,++ep);

  // ================= Prelude B: KAP / UT / CC / BETA tables =================
  {
    int c0 = 2*g;
    float p00 = bv[t]    *Wo[t*256+c0],        p01 = bv[t]    *Wo[t*256+c0+1];
    float p10 = bv[256+t]*Wo[65536+t*256+c0],  p11 = bv[256+t]*Wo[65536+t*256+c0+1];
    p00=wredsum(p00); p01=wredsum(p01); p10=wredsum(p10); p11=wredsum(p11);
    int lane=t&63, wid=t>>6;
    if (lane==0){ sm[wid*4+0]=p00; sm[wid*4+1]=p01; sm[wid*4+2]=p10; sm[wid*4+3]=p11; }
    __syncthreads();
    if (t<4){
      float s=sm[t]+sm[4+t]+sm[8+t]+sm[12+t];
      int i=t>>1, cl=t&1;
      CC[i*256+c0+cl] = s + bo[i*256+c0+cl];
    }
    if (t<32){
      int i=t>>4, h=(t>>1)&7, c=c0+(t&1);
      float s=0.f;
      for (int e2=0;e2<32;e2++) s += SVC[i*256+h*32+e2]*Wo[i*65536+(h*32+e2)*256+c];
      UT[(i*8+h)*256+c]=s;
    }
    if (t>=32 && t<64){
      int u=t-32, i=u>>4, h=(u>>1)&7, e=c0+(u&1);
      float s=0.f;
      for (int c2=0;c2<32;c2++) s += Wq[i*65536+e*256+h*32+c2]*SKC[i*256+h*32+c2];
      KAP[(i*8+h)*256+e]=s;
    }
    if (g==0 && t>=64 && t<80){
      int u=t-64, i=u>>3, h=u&7;
      float s=0.f;
      for (int c2=0;c2<32;c2++) s += bq[i*256+h*32+c2]*SKC[i*256+h*32+c2];
      BETA[i*8+h]=s;
    }
  }
  gbar_f(ARR,REL,++ep);

  if (t<64) wvl[t]=WVEC[t];
  __syncthreads();

  const int h  = g&7;
  const int rg = g>>3;

  // ================= decode loop: 4 master/release barriers + mini =================
  for (int tok=1; tok<64; tok++){
    const int n = tok-1;

    // ---- S1: R1 for own 4 rows (wave-per-row) + self0 Q/K/V proj ----
    {
      const int j=t>>6, l=t&63, l8=l&7, h2=l>>3;
      const int q=rg+16*j;
      if (q<tok){
        float* x = xs + j*256;
        if (q==n && tok>1){
          // SLOTS[n] complete: barrier #4 of iter n drained all atomicMax ops
          unsigned long long s = __hip_atomic_load(&SLOTS[n], __ATOMIC_RELAXED, __HIP_MEMORY_SCOPE_AGENT);
          int v = (int)(~(unsigned int)(s & 0xffffffffull));
          if (h==0 && l==0) out[q]=v;
#pragma unroll
          for (int ii=0;ii<4;ii++){
            int e=l+64*ii;
            float yv = emb[v*256+e] + pe_val(q,e);
            x[e]=yv;
            if (h==0) st_c(&Yg[q*256+e], yv);
          }
        } else {
#pragma unroll
          for (int ii=0;ii<4;ii++){ int e=l+64*ii; x[e]=ld_c(&Yg[q*256+e]); }
        }
        float wreg[8];
#pragma unroll
        for (int m=0;m<8;m++) wreg[m]=wvl[l8+8*m];
#pragma unroll
        for (int b=0;b<2;b++){
          float part=0.f;
#pragma unroll 8
          for (int jj=l8; jj<256; jj+=8) part += x[jj]*KAP[(b*8+h2)*256+jj];
          part += __shfl_xor(part,1,64);
          part += __shfl_xor(part,2,64);
          part += __shfl_xor(part,4,64);
          float alpha=(part+BETA[b*8+h2])*ISQ;
          float mx=-3.4e38f;
#pragma unroll
          for (int m=0;m<8;m++){ int k=l8+8*m; if (k<tok) mx=fmaxf(mx, alpha*wreg[m]); }
          mx=fmaxf(mx,__shfl_xor(mx,1,64));
          mx=fmaxf(mx,__shfl_xor(mx,2,64));
          mx=fmaxf(mx,__shfl_xor(mx,4,64));
          float num=0.f, den=0.f;
#pragma unroll
          for (int m=0;m<8;m++){
            int k=l8+8*m;
            if (k<tok){ float e_=expf(alpha*wreg[m]-mx); num+=e_*wreg[m]; den+=e_; }
          }
          num+=__shfl_xor(num,1,64); num+=__shfl_xor(num,2,64); num+=__shfl_xor(num,4,64);
          den+=__shfl_xor(den,1,64); den+=__shfl_xor(den,2,64); den+=__shfl_xor(den,4,64);
          if (l8==0) m8s[j*8+h2]=num/den;
          float zvv[4], s_=0.f, sq_=0.f;
#pragma unroll
          for (int ii=0;ii<4;ii++){
            int e=l+64*ii;
            float z=CC[b*256+e]+x[e];
#pragma unroll
            for (int hh=0;hh<8;hh++) z += m8s[j*8+hh]*UT[(b*8+hh)*256+e];
            zvv[ii]=z; s_+=z; sq_+=z*z;
          }
          s_=wredsum(s_); sq_=wredsum(sq_);
          float mu=s_*(1.f/256.f), var=sq_*(1.f/256.f)-mu*mu, rstd=1.f/sqrtf(var+1e-5f);
#pragma unroll
          for (int ii=0;ii<4;ii++){
            int e=l+64*ii;
            x[e]=(zvv[ii]-mu)*rstd*lng[b*256+e]+lnb[b*256+e];
          }
        }
      }
      __syncthreads();   // xs (R1 rows) ready for all 4 waves
      // self0 Q/K/V projection, head h, 4 rows (Q -> LDS only)
      int c=t&31, epp=t>>5;
      const int col=h*32+c;
      float aq[4]={0,0,0,0}, ak[4]={0,0,0,0}, av[4]={0,0,0,0};
#pragma unroll 8
      for (int e=epp*32; e<epp*32+32; e++){
        float wq_=Wq[e*256+col], wk_=Wk[e*256+col], wv_=Wv[e*256+col];
#pragma unroll
        for (int jj=0;jj<4;jj++){ float r=xs[jj*256+e]; aq[jj]+=r*wq_; ak[jj]+=r*wk_; av[jj]+=r*wv_; }
      }
#pragma unroll
      for (int jj=0;jj<4;jj++){
        aq[jj]+=__shfl_xor(aq[jj],32,64);
        ak[jj]+=__shfl_xor(ak[jj],32,64);
        av[jj]+=__shfl_xor(av[jj],32,64);
      }
      float4* redq=(float4*)(sm+1056); float4* redk=(float4*)(sm+1568); float4* redv4=(float4*)(sm+2080);
      int lane=t&63, wid=t>>6;
      if (lane<32){
        redq[wid*32+lane]=make_float4(aq[0],aq[1],aq[2],aq[3]);
        redk[wid*32+lane]=make_float4(ak[0],ak[1],ak[2],ak[3]);
        redv4[wid*32+lane]=make_float4(av[0],av[1],av[2],av[3]);
      }
      __syncthreads();
      if (t<32){
        float4 A=redq[t],B4=redq[32+t],C4=redq[64+t],D4=redq[96+t];
        float sq[4]={A.x+B4.x+C4.x+D4.x, A.y+B4.y+C4.y+D4.y, A.z+B4.z+C4.z+D4.z, A.w+B4.w+C4.w+D4.w};
        A=redk[t];B4=redk[32+t];C4=redk[64+t];D4=redk[96+t];
        float sk[4]={A.x+B4.x+C4.x+D4.x, A.y+B4.y+C4.y+D4.y, A.z+B4.z+C4.z+D4.z, A.w+B4.w+C4.w+D4.w};
        A=redv4[t];B4=redv4[32+t];C4=redv4[64+t];D4=redv4[96+t];
        float sv[4]={A.x+B4.x+C4.x+D4.x, A.y+B4.y+C4.y+D4.y, A.z+B4.z+C4.z+D4.z, A.w+B4.w+C4.w+D4.w};
        int cc=h*32+t;
        float bq_=bq[cc], bk_=bk[cc], bv_=bv[cc];
#pragma unroll
        for (int jj=0;jj<4;jj++){
          qs[jj*32+t]=sq[jj]+bq_;
          int q_=rg+16*jj;
          if (q_<tok){
            st_c(&KB[q_*256+cc], sk[jj]+bk_);
            st_c(&VB[q_*256+cc], sv[jj]+bv_);
          }
        }
      }
    }
    gbar_nf(ARR,REL,++ep);

    // ---- S2: self0 attention + per-head partial O-proj -> Z2P ----
    {
      float* Ks=sm; float* Vs=sm+2112; float* arow=sm+4352; float* o2s=sm+4608;
      int k=t>>2, f0=(t&3)*8;
      if (k<tok){
#pragma unroll
        for (int i2=0;i2<8;i2++){
          Ks[k*33+f0+i2]=ld_c(&KB[k*256+h*32+f0+i2]);
          Vs[k*33+f0+i2]=ld_c(&VB[k*256+h*32+f0+i2]);
        }
      }
      __syncthreads();
      int w=t>>6, lane=t&63; int q_=rg+16*w; bool ok=q_<tok;
      float sc=-3.4e38f;
      if (ok && lane<tok){
        sc=0.f;
#pragma unroll
        for (int c2=0;c2<32;c2++) sc+=qs[w*32+c2]*Ks[lane*33+c2];
        sc*=ISQ;
      }
      float mx=wredmax(sc);
      float ex=(ok&&lane<tok)? expf(sc-mx):0.f;
      float sd=wredsum(ex);
      arow[w*64+lane]= ok ? ex/sd : 0.f;
      __syncthreads();
      int jl=lane&31, half=lane>>5;
      float oa=0.f;
      if (ok){ for (int k2=half;k2<tok;k2+=2) oa+=arow[w*64+k2]*Vs[k2*33+jl]; }
      oa += __shfl_xor(oa,32,64);
      if (lane<32) o2s[w*32+jl]=oa;
      __syncthreads();
      float acc[4]={0,0,0,0};
#pragma unroll 8
      for (int j2=0;j2<32;j2++){
        float wv_=Wo[(h*32+j2)*256+t];
#pragma unroll
        for (int jj=0;jj<4;jj++) acc[jj]+=o2s[jj*32+j2]*wv_;
      }
#pragma unroll
      for (int jj=0;jj<4;jj++){ int q2=rg+16*jj; if (q2<tok) st_c(&Z2P[(h*64+q2)*256+t], acc[jj]); }
    }
    gbar_nf(ARR,REL,++ep);

    // ---- S3: z2 assemble + LN -> R2[n] ; self1 K/V proj (+Q1 row n -> LDS) ----
    {
      float* rows4=sm; float* mus=sm+1024;
#pragma unroll
      for (int jj=0;jj<4;jj++){
        int q_=rg+16*jj;
        float z = bo[t] + xs[jj*256+t];
#pragma unroll
        for (int h2=0;h2<8;h2++) z += ld_c(&Z2P[(h2*64+q_)*256+t]);
        rows4[jj*256+t]=z;
      }
      __syncthreads();
      {
        int w=t>>6, lane=t&63;
        float v0=rows4[w*256+lane], v1=rows4[w*256+64+lane], v2=rows4[w*256+128+lane], v3=rows4[w*256+192+lane];
        float s=v0+v1+v2+v3, sq2=v0*v0+v1*v1+v2*v2+v3*v3;
        s=wredsum(s); sq2=wredsum(sq2);
        if (lane==0){
          float mu=s*(1.f/256.f);
          float var=sq2*(1.f/256.f)-mu*mu;
          mus[w*2]=mu; mus[w*2+1]=1.f/sqrtf(var+1e-5f);
        }
      }
      __syncthreads();
#pragma unroll
      for (int jj=0;jj<4;jj++){
        float mu=mus[jj*2], rstd=mus[jj*2+1];
        float val=(rows4[jj*256+t]-mu)*rstd*lng[t]+lnb[t];
        rows4[jj*256+t]=val;
        int q_=rg+16*jj;
        if (h==0 && q_==n) st_c(&R2[q_*256+t], val);
      }
      __syncthreads();
      int c=t&31, epp=t>>5;
      const int col=h*32+c;
      float aq[4]={0,0,0,0}, ak[4]={0,0,0,0}, av[4]={0,0,0,0};
#pragma unroll 8
      for (int e=epp*32; e<epp*32+32; e++){
        float wq_=Wq[65536+e*256+col], wk_=Wk[65536+e*256+col], wv_=Wv[65536+e*256+col];
#pragma unroll
        for (int jj=0;jj<4;jj++){ float r=rows4[jj*256+e]; aq[jj]+=r*wq_; ak[jj]+=r*wk_; av[jj]+=r*wv_; }
      }
#pragma unroll
      for (int jj=0;jj<4;jj++){
        aq[jj]+=__shfl_xor(aq[jj],32,64);
        ak[jj]+=__shfl_xor(ak[jj],32,64);
        av[jj]+=__shfl_xor(av[jj],32,64);
      }
      float4* redq=(float4*)(sm+1056); float4* redk=(float4*)(sm+1568); float4* redv4=(float4*)(sm+2080);
      int lane=t&63, wid=t>>6;
      if (lane<32){
        redq[wid*32+lane]=make_float4(aq[0],aq[1],aq[2],aq[3]);
        redk[wid*32+lane]=make_float4(ak[0],ak[1],ak[2],ak[3]);
        redv4[wid*32+lane]=make_float4(av[0],av[1],av[2],av[3]);
      }
      __syncthreads();
      if (t<32){
        float4 A=redq[t],B4=redq[32+t],C4=redq[64+t],D4=redq[96+t];
        float sq[4]={A.x+B4.x+C4.x+D4.x, A.y+B4.y+C4.y+D4.y, A.z+B4.z+C4.z+D4.z, A.w+B4.w+C4.w+D4.w};
        A=redk[t];B4=redk[32+t];C4=redk[64+t];D4=redk[96+t];
        float sk[4]={A.x+B4.x+C4.x+D4.x, A.y+B4.y+C4.y+D4.y, A.z+B4.z+C4.z+D4.z, A.w+B4.w+C4.w+D4.w};
        A=redv4[t];B4=redv4[32+t];C4=redv4[64+t];D4=redv4[96+t];
        float sv[4]={A.x+B4.x+C4.x+D4.x, A.y+B4.y+C4.y+D4.y, A.z+B4.z+C4.z+D4.z, A.w+B4.w+C4.w+D4.w};
        int cc=h*32+t;
#pragma unroll
        for (int jj=0;jj<4;jj++){
          int q_=rg+16*jj;
          if (q_<tok){
            st_c(&KB[q_*256+cc], sk[jj]+bk[256+cc]);
            st_c(&VB[q_*256+cc], sv[jj]+bv[256+cc]);
          }
          if (q_==n) qn1[t]=sq[jj]+bq[256+cc];
        }
      }
    }
    gbar_nf(ARR,REL,++ep);

    // ---- S4: self1 attn row n (8 WGs -> Z3P + Z3F) ; all: z3 LN + logits + argmax ----
    {
      float resid = ld_c(&R2[n*256+t]);   // early issue; valid after B3
      if (rg == (n&15)){
        float* Ks=sm; float* Vs=sm+2112; float* arow=sm+4352; float* o3s=sm+4608;
        int k=t>>2, f0=(t&3)*8;
        if (k<tok){
#pragma unroll
          for (int i2=0;i2<8;i2++){
            Ks[k*33+f0+i2]=ld_c(&KB[k*256+h*32+f0+i2]);
            Vs[k*33+f0+i2]=ld_c(&VB[k*256+h*32+f0+i2]);
          }
        }
        __syncthreads();
        int lane=t&63, w=t>>6;
        if (w==0){
          float sc=-3.4e38f;
          if (lane<tok){
            sc=0.f;
#pragma unroll
            for (int c2=0;c2<32;c2++) sc+=qn1[c2]*Ks[lane*33+c2];
            sc*=ISQ;
          }
          float mx=wredmax(sc);
          float ex=(lane<tok)? expf(sc-mx):0.f;
          float sd=wredsum(ex);
          arow[lane]=ex/sd;
        }
        __syncthreads();
        if (w==0){
          int jl=lane&31, half=lane>>5;
          float oa=0.f;
          for (int k2=half;k2<tok;k2+=2) oa+=arow[k2]*Vs[k2*33+jl];
          oa+=__shfl_xor(oa,32,64);
          if (lane<32) o3s[jl]=oa;
        }
        __syncthreads();
        float acc=0.f;
#pragma unroll 8
        for (int j2=0;j2<32;j2++) acc+=o3s[j2]*Wo[65536+(h*32+j2)*256+t];
        st_c(&Z3P[h*256+t], acc);
        __syncthreads();            // drain Z3P stores to LLC
        if (t==0) st_fi(Z3F + h*16, tok);
      }
      // mini-barrier: wait for the 8 head partials (flags monotone = tok)
      if (t<8){ while (ld_fi(Z3F + t*16) < tok) __builtin_amdgcn_s_sleep(1); }
      __syncthreads();
      float* outn=sm; float* redv=sm+256; float* pp=sm+512;
      float z = bo[256+t] + resid;
#pragma unroll
      for (int h2=0;h2<8;h2++) z += ld_c(&Z3P[h2*256+t]);
      float s=wredsum(z), sq2=wredsum(z*z);
      int lane=t&63, wid=t>>6;
      if (lane==0){ redv[wid]=s; redv[4+wid]=sq2; }
      __syncthreads();
      float ts=redv[0]+redv[1]+redv[2]+redv[3];
      float tq=redv[4]+redv[5]+redv[6]+redv[7];
      float mu=ts*(1.f/256.f);
      float var=tq*(1.f/256.f)-mu*mu;
      float rstd=1.f/sqrtf(var+1e-5f);
      outn[t]=(z-mu)*rstd*lng[256+t]+lnb[256+t];
      __syncthreads();
      const int c = t & 127, half = t >> 7;
      float acc = 0.f;
      if (c < 125){
        const int e0 = half*128;
#pragma unroll 8
        for (int e=e0; e<e0+128; e++) acc += outn[e]*swl[e*128+c];
      }
      if (half==1 && c<125) pp[c]=acc;
      __syncthreads();
      unsigned long long key=0ull;
      if (half==0 && c<125){
        int v=g*125+c;
        float a2 = acc + pp[c] + sb[v];
        unsigned int fb=__float_as_uint(a2);
        fb = (fb&0x80000000u)? ~fb : (fb|0x80000000u);
        key=(((unsigned long long)fb)<<32) | (unsigned long long)(~(unsigned int)v);
      }
#pragma unroll
      for (int m=32;m;m>>=1){
        unsigned long long o=shflx64(key,m);
        key = (o>key)? o : key;
      }
      if (lane==0) redU[wid]=key;
      __syncthreads();
      if (t==0){
        unsigned long long kk=redU[0];
        if (redU[1]>kk) kk=redU[1];
        if (redU[2]>kk) kk=redU[2];
        if (redU[3]>kk) kk=redU[3];
        atomicMax(&SLOTS[tok], kk);
      }
    }
    gbar_nf(ARR,REL,++ep);   // B4: orders SLOTS merge + KB/VB WAR for S1(t+1)
  }

  // epilogue: final winner (B4 of tok=63 already ordered the merge)
  if (g==0 && t==0){
    unsigned long long s=__hip_atomic_load(&SLOTS[63],__ATOMIC_RELAXED,__HIP_MEMORY_SCOPE_AGENT);
    out[63]=(int)(~(unsigned int)(s&0xffffffffull));
  }
}

extern "C" void kernel_launch(void* const* d_in, const int* in_sizes, int n_in,
                              void* d_out, int out_size, void* d_ws, size_t ws_size,
                              hipStream_t stream)
{
  (void)in_sizes; (void)n_in; (void)out_size; (void)ws_size;
  hipLaunchKernelGGL(gen18124_kernel, dim3(NWG), dim3(NT), 131072, stream,
    (const float*)d_in[0],  (const float*)d_in[1],  (const float*)d_in[2],
    (const float*)d_in[3],  (const float*)d_in[4],  (const float*)d_in[5],
    (const float*)d_in[6],  (const float*)d_in[7],  (const float*)d_in[8],
    (const float*)d_in[9],  (const float*)d_in[10], (const float*)d_in[11],
    (const float*)d_in[12], (const float*)d_in[13], (const float*)d_in[14],
    (const float*)d_in[15], (int*)d_out, (float*)d_ws);
}

// Round 4
// 4125.513 us; speedup vs baseline: 1.5720x; 1.5124x over previous
//
#include <hip/hip_runtime.h>
#include <stdint.h>

// R7 = R3 (proven 4291us base) + ONE structural delta:
//  - Stage F merged into H via the 8-flag Z3F mini-barrier (proven correct in
//    R4/R6): F's 8 WGs write Z3P, drain (syncthreads), set per-head flag
//    (value=tok, monotone, distinct LLC lines); all WGs poll 8 flags instead
//    of a full 2-hop global barrier. 6 global barriers/iter -> 5 + mini.
//  - SLOT -> SLOTS[64] (prelude-zeroed), removing the stage-B reset.
//  Post-mortem R4-R6: the 4-stage restructure (redundant 16x R1 compute) was
//  the regression (6.2ms/468MB at 3 different barrier types); reverted.

#define NWG 128
#define NT 256

__device__ __forceinline__ float ld_c(const float* p){
  return __hip_atomic_load(p, __ATOMIC_RELAXED, __HIP_MEMORY_SCOPE_AGENT);
}
__device__ __forceinline__ void st_c(float* p, float v){
  __hip_atomic_store(p, v, __ATOMIC_RELAXED, __HIP_MEMORY_SCOPE_AGENT);
}
__device__ __forceinline__ int ld_fi(const int* p){
  return __hip_atomic_load(p, __ATOMIC_RELAXED, __HIP_MEMORY_SCOPE_AGENT);
}
__device__ __forceinline__ void st_fi(int* p, int v){
  __hip_atomic_store(p, v, __ATOMIC_RELAXED, __HIP_MEMORY_SCOPE_AGENT);
}

__device__ __forceinline__ float wredsum(float v){
#pragma unroll
  for (int m=32;m;m>>=1) v += __shfl_xor(v,m,64);
  return v;
}
__device__ __forceinline__ float wredmax(float v){
#pragma unroll
  for (int m=32;m;m>>=1) v = fmaxf(v,__shfl_xor(v,m,64));
  return v;
}
__device__ __forceinline__ float g32sum(float v){
#pragma unroll
  for (int m=16;m;m>>=1) v += __shfl_xor(v,m,64);
  return v;
}
__device__ __forceinline__ float g32max(float v){
#pragma unroll
  for (int m=16;m;m>>=1) v = fmaxf(v,__shfl_xor(v,m,64));
  return v;
}
__device__ __forceinline__ unsigned long long shflx64(unsigned long long v,int m){
  unsigned int lo=(unsigned int)(v&0xffffffffull), hi=(unsigned int)(v>>32);
  lo=__shfl_xor(lo,m,64); hi=__shfl_xor(hi,m,64);
  return (((unsigned long long)hi)<<32)|(unsigned long long)lo;
}

__device__ __forceinline__ float pe_val(int l, int e){
  int j = e >> 1;
  float dv = expf((float)(2*j) * (-0.035977892078031970f));
  float arg = (float)l * dv;
  return (e & 1) ? cosf(arg) : sinf(arg);
}

// fenced barrier (prelude only): publishes normal cached stores
__device__ __forceinline__ void gbar_f(int* arr, int* rel, int ep){
  __syncthreads();
  if (threadIdx.x==0){
    __builtin_amdgcn_fence(__ATOMIC_RELEASE, "agent");
    __hip_atomic_store(arr + blockIdx.x*16, ep, __ATOMIC_RELAXED, __HIP_MEMORY_SCOPE_AGENT);
  }
  if (blockIdx.x==0){
    if (threadIdx.x < NWG){
      while (__hip_atomic_load(arr + threadIdx.x*16, __ATOMIC_RELAXED, __HIP_MEMORY_SCOPE_AGENT) != ep)
        __builtin_amdgcn_s_sleep(1);
    }
    __syncthreads();
    if (threadIdx.x==0)
      __hip_atomic_store(rel, ep, __ATOMIC_RELAXED, __HIP_MEMORY_SCOPE_AGENT);
  }
  if (threadIdx.x==0){
    while (__hip_atomic_load(rel, __ATOMIC_RELAXED, __HIP_MEMORY_SCOPE_AGENT) != ep)
      __builtin_amdgcn_s_sleep(1);
    __builtin_amdgcn_fence(__ATOMIC_ACQUIRE, "agent");
  }
  __syncthreads();
}

// fence-free barrier (decode loop): all cross-WG data moves via sc1 atomics,
// __syncthreads drains vmcnt so sc1 stores are LLC-visible before arrive.
__device__ __forceinline__ void gbar_nf(int* arr, int* rel, int ep){
  __syncthreads();
  if (threadIdx.x==0)
    __hip_atomic_store(arr + blockIdx.x*16, ep, __ATOMIC_RELAXED, __HIP_MEMORY_SCOPE_AGENT);
  if (blockIdx.x==0){
    if (threadIdx.x < NWG){
      while (__hip_atomic_load(arr + threadIdx.x*16, __ATOMIC_RELAXED, __HIP_MEMORY_SCOPE_AGENT) != ep)
        __builtin_amdgcn_s_sleep(1);
    }
    __syncthreads();
    if (threadIdx.x==0)
      __hip_atomic_store(rel, ep, __ATOMIC_RELAXED, __HIP_MEMORY_SCOPE_AGENT);
  }
  if (threadIdx.x==0){
    while (__hip_atomic_load(rel, __ATOMIC_RELAXED, __HIP_MEMORY_SCOPE_AGENT) != ep)
      __builtin_amdgcn_s_sleep(1);
  }
  __syncthreads();
}

extern "C" __global__ __launch_bounds__(256, 2)
void gen18124_kernel(const float* __restrict__ noise,
                     const float* __restrict__ iw, const float* __restrict__ ib,
                     const float* __restrict__ Wq, const float* __restrict__ bq,
                     const float* __restrict__ Wk, const float* __restrict__ bk,
                     const float* __restrict__ Wv, const float* __restrict__ bv,
                     const float* __restrict__ Wo, const float* __restrict__ bo,
                     const float* __restrict__ lng, const float* __restrict__ lnb,
                     const float* __restrict__ emb, const float* __restrict__ sw,
                     const float* __restrict__ sb,
                     int* __restrict__ out, float* __restrict__ ws)
{
  const float ISQ = 0.17677669529663687f; // 1/sqrt(32)
  __shared__ float sm[5376];
  __shared__ unsigned long long redU[4];
  extern __shared__ float swl[];          // [256][128] soft_W slice, 128KB

  // ---- workspace layout (floats) ----
  float* WVEC = ws;            // 64
  float* SKC  = ws+64;         // [2][256] colsum(Wk)
  float* SVC  = ws+576;        // [2][256] colsum(Wv)
  float* KAP  = ws+1088;       // [2][8][256]
  float* UT   = ws+5184;       // [2][8][256]
  float* CC   = ws+9280;       // [2][256]
  float* BETA = ws+9792;       // [2][8]
  unsigned long long* SLOTS = (unsigned long long*)(ws+9824); // [64]
  int* Z3F = (int*)(ws+9952);  // 8 * stride16 (mini-barrier flags)
  int* ARR = (int*)(ws+10080); // 128 * stride16 ints
  int* REL = (int*)(ws+12128);
  float* Yg  = ws+14208;       // [64][256]
  float* R1  = ws+30592;       // [64][256]
  float* QB  = ws+46976;       // [64][256]
  float* KB  = ws+63360;       // [64][256]
  float* VB  = ws+79744;       // [64][256]
  float* R2  = ws+96128;       // [64][256]
  float* Z2P = ws+112512;      // [8][64][256]
  float* Z3P = ws+243584;      // [8][256]

  const int g = blockIdx.x, t = threadIdx.x;
  int ep = 0;

  // ---- soft_W slice -> LDS (WG-private, no barrier needed) ----
  {
    const int base = g*125;
#pragma unroll 8
    for (int i=t; i<256*128; i+=NT){
      int e=i>>7, c=i&127;
      float val = 0.f;
      if (c<125) val = sw[e*16000 + base + c];
      swl[i]=val;
    }
  }

  // ================= Prelude A: colsums, wvec, Y0, slot/out init =================
  {
    int c0 = 2*g;
    float a0=Wk[t*256+c0],       a1=Wk[t*256+c0+1];
    float a2=Wk[65536+t*256+c0], a3=Wk[65536+t*256+c0+1];
    float a4=Wv[t*256+c0],       a5=Wv[t*256+c0+1];
    float a6=Wv[65536+t*256+c0], a7=Wv[65536+t*256+c0+1];
    a0=wredsum(a0); a1=wredsum(a1); a2=wredsum(a2); a3=wredsum(a3);
    a4=wredsum(a4); a5=wredsum(a5); a6=wredsum(a6); a7=wredsum(a7);
    int lane=t&63, wid=t>>6;
    if (lane==0){
      sm[wid*8+0]=a0; sm[wid*8+1]=a1; sm[wid*8+2]=a2; sm[wid*8+3]=a3;
      sm[wid*8+4]=a4; sm[wid*8+5]=a5; sm[wid*8+6]=a6; sm[wid*8+7]=a7;
    }
    __syncthreads();
    if (t<8){
      float s=sm[t]+sm[8+t]+sm[16+t]+sm[24+t];
      if (t<4) SKC[(t>>1)*256 + c0 + (t&1)] = s;
      else     SVC[((t-4)>>1)*256 + c0 + ((t-4)&1)] = s;
    }
    __syncthreads();
    if (g==0){
      if (t<64) SLOTS[t]=0ull;
      if (t<8)  Z3F[t*16]=0;
      float* wl = sm+64;
      if (t<64) wl[t] = noise[t];
      __syncthreads();
      for (int i=0;i<4;i++){
        float acc=0.f;
        if (t<64){
          for (int in_=0;in_<64;in_++) acc += wl[in_]*iw[(i*64+in_)*64+t];
          acc += ib[i*64+t];
        }
        __syncthreads();
        if (t<64) wl[t]=acc;
        __syncthreads();
      }
      if (t<64) WVEC[t]=wl[t];
    }
    if (g==1){
      Yg[t] = emb[t] + pe_val(0,t);   // normal store; published by fenced prelude barriers
      if (t==0) out[0]=0;
    }
  }
  gbar_f(ARR,REL,++ep);

  // ================= Prelude B: KAP / UT / CC / BETA tables =================
  {
    int c0 = 2*g;
    float p00 = bv[t]    *Wo[t*256+c0],        p01 = bv[t]    *Wo[t*256+c0+1];
    float p10 = bv[256+t]*Wo[65536+t*256+c0],  p11 = bv[256+t]*Wo[65536+t*256+c0+1];
    p00=wredsum(p00); p01=wredsum(p01); p10=wredsum(p10); p11=wredsum(p11);
    int lane=t&63, wid=t>>6;
    if (lane==0){ sm[wid*4+0]=p00; sm[wid*4+1]=p01; sm[wid*4+2]=p10; sm[wid*4+3]=p11; }
    __syncthreads();
    if (t<4){
      float s=sm[t]+sm[4+t]+sm[8+t]+sm[12+t];
      int i=t>>1, cl=t&1;
      CC[i*256+c0+cl] = s + bo[i*256+c0+cl];
    }
    if (t<32){
      int i=t>>4, h=(t>>1)&7, c=c0+(t&1);
      float s=0.f;
      for (int e2=0;e2<32;e2++) s += SVC[i*256+h*32+e2]*Wo[i*65536+(h*32+e2)*256+c];
      UT[(i*8+h)*256+c]=s;
    }
    if (t>=32 && t<64){
      int u=t-32, i=u>>4, h=(u>>1)&7, e=c0+(u&1);
      float s=0.f;
      for (int c2=0;c2<32;c2++) s += Wq[i*65536+e*256+h*32+c2]*SKC[i*256+h*32+c2];
      KAP[(i*8+h)*256+e]=s;
    }
    if (g==0 && t>=64 && t<80){
      int u=t-64, i=u>>3, h=u&7;
      float s=0.f;
      for (int c2=0;c2<32;c2++) s += bq[i*256+h*32+c2]*SKC[i*256+h*32+c2];
      BETA[i*8+h]=s;
    }
  }
  gbar_f(ARR,REL,++ep);

  // ================= decode loop (5 barriers + mini, fence-free) ======
  for (int tok=1; tok<64; tok++){
    const int n = tok-1;

    // ---- Stage A: WG-per-row, both cross blocks (rank-1 collapsed) -> r1 ----
    if (g < tok){
      const int q = g;
      float* xrow = sm; float* rrow = sm+256; float* m8 = sm+512; float* redv = sm+528;
      if (q==n && tok>1){
        unsigned long long s = __hip_atomic_load(&SLOTS[n], __ATOMIC_RELAXED, __HIP_MEMORY_SCOPE_AGENT);
        int v = (int)(~(unsigned int)(s & 0xffffffffull));
        if (t==0) out[q]=v;
        float yv = emb[v*256+t] + pe_val(q,t);
        xrow[t]=yv; st_c(&Yg[q*256+t], yv);
      } else {
        xrow[t]=ld_c(&Yg[q*256+t]);
      }
      __syncthreads();
      for (int blk=0; blk<2; blk++){
        const float* src = blk ? rrow : xrow;
        int h=t>>5, j=t&31;
        float part=0.f;
        for (int jj=j; jj<256; jj+=32) part += src[jj]*KAP[(blk*8+h)*256+jj];
        part = g32sum(part);
        float alpha = (part + BETA[blk*8+h]) * ISQ;
        float s1 = (j<tok)     ? alpha*WVEC[j]    : -3.4e38f;
        float s2 = (j+32<tok)  ? alpha*WVEC[j+32] : -3.4e38f;
        float mx = g32max(fmaxf(s1,s2));
        float e1 = expf(s1-mx), e2 = expf(s2-mx);
        float sn = e1*((j<tok)?WVEC[j]:0.f) + e2*((j+32<tok)?WVEC[j+32]:0.f);
        float sd = e1+e2;
        sn=g32sum(sn); sd=g32sum(sd);
        if (j==0) m8[h]=sn/sd;
        __syncthreads();
        float x_ = blk ? rrow[t] : xrow[t];
        float z = CC[blk*256+t] + x_;
#pragma unroll
        for (int h2=0;h2<8;h2++) z += m8[h2]*UT[(blk*8+h2)*256+t];
        float ssum=wredsum(z), ssq=wredsum(z*z);
        int lane=t&63, wid=t>>6;
        if (lane==0){ redv[wid]=ssum; redv[4+wid]=ssq; }
        __syncthreads();
        float ts=redv[0]+redv[1]+redv[2]+redv[3];
        float tq=redv[4]+redv[5]+redv[6]+redv[7];
        float mu=ts*(1.f/256.f);
        float var=tq*(1.f/256.f)-mu*mu;
        float rstd=1.f/sqrtf(var+1e-5f);
        float rv=(z-mu)*rstd*lng[blk*256+t]+lnb[blk*256+t];
        __syncthreads();
        rrow[t]=rv;
        __syncthreads();
      }
      st_c(&R1[q*256+t], rrow[t]);
    }
    gbar_nf(ARR,REL,++ep);

    // ---- Stage B: self0 Q/K/V projection, (rowgroup, head) mapping ----
    {
      const int h=g&7, rg=g>>3;
      float* rows4 = sm; // [4][256]
#pragma unroll
      for (int jj=0;jj<4;jj++) rows4[jj*256+t] = ld_c(&R1[(rg+16*jj)*256+t]);
      __syncthreads();
      int c=t&31, epp=t>>5;
      const int col=h*32+c;
      float aq[4]={0,0,0,0}, ak[4]={0,0,0,0}, av[4]={0,0,0,0};
#pragma unroll 8
      for (int e=epp*32; e<epp*32+32; e++){
        float wq_=Wq[e*256+col], wk_=Wk[e*256+col], wv_=Wv[e*256+col];
#pragma unroll
        for (int jj=0;jj<4;jj++){ float r=rows4[jj*256+e]; aq[jj]+=r*wq_; ak[jj]+=r*wk_; av[jj]+=r*wv_; }
      }
#pragma unroll
      for (int jj=0;jj<4;jj++){
        aq[jj]+=__shfl_xor(aq[jj],32,64);
        ak[jj]+=__shfl_xor(ak[jj],32,64);
        av[jj]+=__shfl_xor(av[jj],32,64);
      }
      float4* redq=(float4*)(sm+1056); float4* redk=(float4*)(sm+1568); float4* redv4=(float4*)(sm+2080);
      int lane=t&63, wid=t>>6;
      if (lane<32){
        redq[wid*32+lane]=make_float4(aq[0],aq[1],aq[2],aq[3]);
        redk[wid*32+lane]=make_float4(ak[0],ak[1],ak[2],ak[3]);
        redv4[wid*32+lane]=make_float4(av[0],av[1],av[2],av[3]);
      }
      __syncthreads();
      if (t<32){
        float4 A=redq[t],B4=redq[32+t],C4=redq[64+t],D4=redq[96+t];
        float sq[4]={A.x+B4.x+C4.x+D4.x, A.y+B4.y+C4.y+D4.y, A.z+B4.z+C4.z+D4.z, A.w+B4.w+C4.w+D4.w};
        A=redk[t];B4=redk[32+t];C4=redk[64+t];D4=redk[96+t];
        float sk[4]={A.x+B4.x+C4.x+D4.x, A.y+B4.y+C4.y+D4.y, A.z+B4.z+C4.z+D4.z, A.w+B4.w+C4.w+D4.w};
        A=redv4[t];B4=redv4[32+t];C4=redv4[64+t];D4=redv4[96+t];
        float sv[4]={A.x+B4.x+C4.x+D4.x, A.y+B4.y+C4.y+D4.y, A.z+B4.z+C4.z+D4.z, A.w+B4.w+C4.w+D4.w};
        int cc=h*32+t;
        float bq_=bq[cc], bk_=bk[cc], bv_=bv[cc];
#pragma unroll
        for (int jj=0;jj<4;jj++){
          int q_=rg+16*jj;
          if (q_<tok){
            st_c(&QB[q_*256+cc], sq[jj]+bq_);
            st_c(&KB[q_*256+cc], sk[jj]+bk_);
            st_c(&VB[q_*256+cc], sv[jj]+bv_);
          }
        }
      }
    }
    gbar_nf(ARR,REL,++ep);

    // ---- Stage C: self0 attention + per-head partial O-proj -> Z2P ----
    {
      const int h=g&7, rg=g>>3;
      float* Ks=sm; float* Vs=sm+2112; float* qrow=sm+4224; float* arow=sm+4352; float* o2s=sm+4608;
      int k=t>>2, f0=(t&3)*8;
      if (k<tok){
#pragma unroll
        for (int i2=0;i2<8;i2++){
          Ks[k*33+f0+i2]=ld_c(&KB[k*256+h*32+f0+i2]);
          Vs[k*33+f0+i2]=ld_c(&VB[k*256+h*32+f0+i2]);
        }
      }
      if (t<128){ int jj=t>>5, c=t&31; int q_=rg+16*jj; if (q_<tok) qrow[jj*32+c]=ld_c(&QB[q_*256+h*32+c]); }
      __syncthreads();
      int w=t>>6, lane=t&63; int q_=rg+16*w; bool ok=q_<tok;
      float sc=-3.4e38f;
      if (ok && lane<tok){
        sc=0.f;
#pragma unroll
        for (int c2=0;c2<32;c2++) sc+=qrow[w*32+c2]*Ks[lane*33+c2];
        sc*=ISQ;
      }
      float mx=wredmax(sc);
      float ex=(ok&&lane<tok)? expf(sc-mx):0.f;
      float sd=wredsum(ex);
      arow[w*64+lane]= ok ? ex/sd : 0.f;
      __syncthreads();
      int j=lane&31, half=lane>>5;
      float oa=0.f;
      if (ok){ for (int k2=half;k2<tok;k2+=2) oa+=arow[w*64+k2]*Vs[k2*33+j]; }
      oa += __shfl_xor(oa,32,64);
      if (lane<32) o2s[w*32+j]=oa;
      __syncthreads();
      float acc[4]={0,0,0,0};
#pragma unroll 8
      for (int j2=0;j2<32;j2++){
        float wv_=Wo[(h*32+j2)*256+t];
#pragma unroll
        for (int jj=0;jj<4;jj++) acc[jj]+=o2s[jj*32+j2]*wv_;
      }
#pragma unroll
      for (int jj=0;jj<4;jj++){ int q2=rg+16*jj; if (q2<tok) st_c(&Z2P[(h*64+q2)*256+t], acc[jj]); }
    }
    gbar_nf(ARR,REL,++ep);

    // ---- Stage E: z2 assemble + LN -> r2 ; self1 K/V proj (+Q for row n) ----
    {
      const int h=g&7, rg=g>>3;
      float* rows4=sm; float* mus=sm+1024;
#pragma unroll
      for (int jj=0;jj<4;jj++){
        int q_=rg+16*jj;
        float z = bo[t] + ld_c(&R1[q_*256+t]);
#pragma unroll
        for (int h2=0;h2<8;h2++) z += ld_c(&Z2P[(h2*64+q_)*256+t]);
        rows4[jj*256+t]=z;
      }
      __syncthreads();
      {
        int w=t>>6, lane=t&63;
        float v0=rows4[w*256+lane], v1=rows4[w*256+64+lane], v2=rows4[w*256+128+lane], v3=rows4[w*256+192+lane];
        float s=v0+v1+v2+v3, sq2=v0*v0+v1*v1+v2*v2+v3*v3;
        s=wredsum(s); sq2=wredsum(sq2);
        if (lane==0){
          float mu=s*(1.f/256.f);
          float var=sq2*(1.f/256.f)-mu*mu;
          mus[w*2]=mu; mus[w*2+1]=1.f/sqrtf(var+1e-5f);
        }
      }
      __syncthreads();
#pragma unroll
      for (int jj=0;jj<4;jj++){
        float mu=mus[jj*2], rstd=mus[jj*2+1];
        float val=(rows4[jj*256+t]-mu)*rstd*lng[t]+lnb[t];
        rows4[jj*256+t]=val;
        int q_=rg+16*jj;
        if (h==0 && q_<tok) st_c(&R2[q_*256+t], val);
      }
      __syncthreads();
      int c=t&31, epp=t>>5;
      const int col=h*32+c;
      float aq[4]={0,0,0,0}, ak[4]={0,0,0,0}, av[4]={0,0,0,0};
#pragma unroll 8
      for (int e=epp*32; e<epp*32+32; e++){
        float wq_=Wq[65536+e*256+col], wk_=Wk[65536+e*256+col], wv_=Wv[65536+e*256+col];
#pragma unroll
        for (int jj=0;jj<4;jj++){ float r=rows4[jj*256+e]; aq[jj]+=r*wq_; ak[jj]+=r*wk_; av[jj]+=r*wv_; }
      }
#pragma unroll
      for (int jj=0;jj<4;jj++){
        aq[jj]+=__shfl_xor(aq[jj],32,64);
        ak[jj]+=__shfl_xor(ak[jj],32,64);
        av[jj]+=__shfl_xor(av[jj],32,64);
      }
      float4* redq=(float4*)(sm+1056); float4* redk=(float4*)(sm+1568); float4* redv4=(float4*)(sm+2080);
      int lane=t&63, wid=t>>6;
      if (lane<32){
        redq[wid*32+lane]=make_float4(aq[0],aq[1],aq[2],aq[3]);
        redk[wid*32+lane]=make_float4(ak[0],ak[1],ak[2],ak[3]);
        redv4[wid*32+lane]=make_float4(av[0],av[1],av[2],av[3]);
      }
      __syncthreads();
      if (t<32){
        float4 A=redq[t],B4=redq[32+t],C4=redq[64+t],D4=redq[96+t];
        float sq[4]={A.x+B4.x+C4.x+D4.x, A.y+B4.y+C4.y+D4.y, A.z+B4.z+C4.z+D4.z, A.w+B4.w+C4.w+D4.w};
        A=redk[t];B4=redk[32+t];C4=redk[64+t];D4=redk[96+t];
        float sk[4]={A.x+B4.x+C4.x+D4.x, A.y+B4.y+C4.y+D4.y, A.z+B4.z+C4.z+D4.z, A.w+B4.w+C4.w+D4.w};
        A=redv4[t];B4=redv4[32+t];C4=redv4[64+t];D4=redv4[96+t];
        float sv[4]={A.x+B4.x+C4.x+D4.x, A.y+B4.y+C4.y+D4.y, A.z+B4.z+C4.z+D4.z, A.w+B4.w+C4.w+D4.w};
        int cc=h*32+t;
#pragma unroll
        for (int jj=0;jj<4;jj++){
          int q_=rg+16*jj;
          if (q_<tok){
            st_c(&KB[q_*256+cc], sk[jj]+bk[256+cc]);
            st_c(&VB[q_*256+cc], sv[jj]+bv[256+cc]);
            if (q_==n) st_c(&QB[q_*256+cc], sq[jj]+bq[256+cc]);
          }
        }
      }
    }
    gbar_nf(ARR,REL,++ep);

    // ---- Stage F+H merged: self1 attn row n (8 WGs -> Z3P + Z3F flags);
    //      all WGs: mini-poll, z3 assemble + LN + logits + packed argmax ----
    {
      const int h=g&7, rg=g>>3;
      float resid = ld_c(&R2[n*256+t]);   // early issue; valid after E-barrier
      if (rg == (n&15)){
        float* Ks=sm; float* Vs=sm+2112; float* qn=sm+4224; float* arow=sm+4352; float* o3s=sm+4608;
        int k=t>>2, f0=(t&3)*8;
        if (k<tok){
#pragma unroll
          for (int i2=0;i2<8;i2++){
            Ks[k*33+f0+i2]=ld_c(&KB[k*256+h*32+f0+i2]);
            Vs[k*33+f0+i2]=ld_c(&VB[k*256+h*32+f0+i2]);
          }
        }
        if (t<32) qn[t]=ld_c(&QB[n*256+h*32+t]);
        __syncthreads();
        int lane=t&63, w=t>>6;
        if (w==0){
          float sc=-3.4e38f;
          if (lane<tok){
            sc=0.f;
#pragma unroll
            for (int c2=0;c2<32;c2++) sc+=qn[c2]*Ks[lane*33+c2];
            sc*=ISQ;
          }
          float mx=wredmax(sc);
          float ex=(lane<tok)? expf(sc-mx):0.f;
          float sd=wredsum(ex);
          arow[lane]=ex/sd;
        }
        __syncthreads();
        if (w==0){
          int j=lane&31, half=lane>>5;
          float oa=0.f;
          for (int k2=half;k2<tok;k2+=2) oa+=arow[k2]*Vs[k2*33+j];
          oa+=__shfl_xor(oa,32,64);
          if (lane<32) o3s[j]=oa;
        }
        __syncthreads();
        float acc=0.f;
#pragma unroll 8
        for (int j2=0;j2<32;j2++) acc+=o3s[j2]*Wo[65536+(h*32+j2)*256+t];
        st_c(&Z3P[h*256+t], acc);
        __syncthreads();            // drain Z3P stores to LLC
        if (t==0) st_fi(Z3F + h*16, tok);
      }
      // mini-barrier: wait for the 8 head partials (flags monotone = tok)
      if (t<8){ while (ld_fi(Z3F + t*16) < tok) __builtin_amdgcn_s_sleep(1); }
      __syncthreads();
      float* outn=sm; float* redv=sm+256; float* pp=sm+512;
      float z = bo[256+t] + resid;
#pragma unroll
      for (int h2=0;h2<8;h2++) z += ld_c(&Z3P[h2*256+t]);
      float s=wredsum(z), sq2=wredsum(z*z);
      int lane=t&63, wid=t>>6;
      if (lane==0){ redv[wid]=s; redv[4+wid]=sq2; }
      __syncthreads();
      float ts=redv[0]+redv[1]+redv[2]+redv[3];
      float tq=redv[4]+redv[5]+redv[6]+redv[7];
      float mu=ts*(1.f/256.f);
      float var=tq*(1.f/256.f)-mu*mu;
      float rstd=1.f/sqrtf(var+1e-5f);
      outn[t]=(z-mu)*rstd*lng[256+t]+lnb[256+t];
      __syncthreads();
      const int c = t & 127, half = t >> 7;
      float acc = 0.f;
      if (c < 125){
        const int e0 = half*128;
#pragma unroll 8
        for (int e=e0; e<e0+128; e++) acc += outn[e]*swl[e*128+c];
      }
      if (half==1 && c<125) pp[c]=acc;
      __syncthreads();
      unsigned long long key=0ull;
      if (half==0 && c<125){
        int v=g*125+c;
        float a2 = acc + pp[c] + sb[v];
        unsigned int fb=__float_as_uint(a2);
        fb = (fb&0x80000000u)? ~fb : (fb|0x80000000u);
        key=(((unsigned long long)fb)<<32) | (unsigned long long)(~(unsigned int)v);
      }
#pragma unroll
      for (int m=32;m;m>>=1){
        unsigned long long o=shflx64(key,m);
        key = (o>key)? o : key;
      }
      if (lane==0) redU[wid]=key;
      __syncthreads();
      if (t==0){
        unsigned long long kk=redU[0];
        if (redU[1]>kk) kk=redU[1];
        if (redU[2]>kk) kk=redU[2];
        if (redU[3]>kk) kk=redU[3];
        atomicMax(&SLOTS[tok], kk);
      }
    }
    gbar_nf(ARR,REL,++ep);   // orders SLOTS merge + KB/VB WAR for next iter
  }

  // epilogue: final winner (last barrier ordered the merge)
  if (g==0 && t==0){
    unsigned long long s=__hip_atomic_load(&SLOTS[63],__ATOMIC_RELAXED,__HIP_MEMORY_SCOPE_AGENT);
    out[63]=(int)(~(unsigned int)(s&0xffffffffull));
  }
}

extern "C" void kernel_launch(void* const* d_in, const int* in_sizes, int n_in,
                              void* d_out, int out_size, void* d_ws, size_t ws_size,
                              hipStream_t stream)
{
  (void)in_sizes; (void)n_in; (void)out_size; (void)ws_size;
  hipLaunchKernelGGL(gen18124_kernel, dim3(NWG), dim3(NT), 131072, stream,
    (const float*)d_in[0],  (const float*)d_in[1],  (const float*)d_in[2],
    (const float*)d_in[3],  (const float*)d_in[4],  (const float*)d_in[5],
    (const float*)d_in[6],  (const float*)d_in[7],  (const float*)d_in[8],
    (const float*)d_in[9],  (const float*)d_in[10], (const float*)d_in[11],
    (const float*)d_in[12], (const float*)d_in[13], (const float*)d_in[14],
    (const float*)d_in[15], (int*)d_out, (float*)d_ws);
}